// Round 10
// baseline (82.976 us; speedup 1.0000x reference)
//
#include <hip/hip_runtime.h>
#include <math.h>

// Hexagonal sensor photon binning — R10: 5-deep prefetch ring (MLP attack).
//  * 5 slots x (x,y,v) f32x4 groups in registers; slot processed at i is
//    immediately refilled from i+5*stride -> 15 loads (240B/lane) always in
//    flight, counted vmcnt waits, queue never drains (convoy fix).
//  * __launch_bounds__(256,4) caps VGPR at 128 (4 waves/SIMD).
//  * closed-form hex index, LDS hist, partials flush + reduce (absmax 0.0).

#define FLUSH_P 64

typedef float f32x4 __attribute__((ext_vector_type(4)));

__global__ void hex_zero_kernel(float* __restrict__ p, int n) {
    int i = blockIdx.x * blockDim.x + threadIdx.x;
    if (i < n) p[i] = 0.0f;
}

__global__ __launch_bounds__(256) void hex_reduce_kernel(
    const float* __restrict__ partials, float* __restrict__ out, int n_pixels)
{
    int pix = blockIdx.x * blockDim.x + threadIdx.x;
    if (pix >= n_pixels) return;
    float s = 0.0f;
    #pragma unroll 8
    for (int j = 0; j < FLUSH_P; ++j) s += partials[j * n_pixels + pix];
    out[pix] = s;
}

__global__ __launch_bounds__(256, 4) void hex_bin_kernel(
    const float* __restrict__ x,
    const float* __restrict__ y,
    const float* __restrict__ vals,
    const float* __restrict__ hex_size_p,
    const float* __restrict__ q_off_p,
    const float* __restrict__ r_off_p,
    const int*   __restrict__ q_min_p,
    const int*   __restrict__ r_min_p,
    int Rh,              // hex radius (24)
    int n_pixels, int n_photons,
    float* __restrict__ flush_dst,
    int use_partials)
{
    extern __shared__ float hist[];  // n_pixels floats
    for (int i = threadIdx.x; i < n_pixels; i += blockDim.x) hist[i] = 0.0f;
    __syncthreads();

    const float inv_h = 1.0f / hex_size_p[0];
    const float A  = 0.57735026918962576f * inv_h;
    const float Bn = -(0.33333333333333333f * inv_h);
    const float C  = 0.66666666666666667f * inv_h;
    const float qc = -q_off_p[0];
    const float rc = -r_off_p[0];
    const int   qmin = q_min_p[0];
    const int   rmin = r_min_p[0];

    const unsigned twoR = (unsigned)(2 * Rh);
    const int Rp1 = Rh + 1;

    auto process = [&](float xf, float yf, float vf) {
        float q = fmaf(A, xf, fmaf(Bn, yf, qc));
        float r = fmaf(C, yf, rc);
        float t = q + r;                  // s = -t, sr = -rintf(t)
        float qr = rintf(q);
        float rr = rintf(r);
        float tr = rintf(t);
        float qd = fabsf(qr - q);
        float rd = fabsf(rr - r);
        float td = fabsf(tr - t);         // == sd
        float q2 = (qd > rd && qd > td) ? (tr - rr) : qr;
        float r2 = (rd > qd && rd > td) ? (tr - qr) : rr;
        int qi = (int)q2 - qmin;
        int ri = (int)r2 - rmin;
        int d  = qi + ri;
        if ((unsigned)qi <= twoR && (unsigned)ri <= twoR &&
            (unsigned)(d - Rh) <= twoR) {
            int u  = max(qi - Rh, 0);
            int p  = qi * Rp1 + ((qi * qi - qi) >> 1) + d - Rh - u * u;
            atomicAdd(&hist[p], vf);      // ds_add_f32 (no return)
        }
    };

    const int tid    = blockIdx.x * blockDim.x + threadIdx.x;
    const int stride = gridDim.x * blockDim.x;
    const int n4     = n_photons >> 2;   // 4-photon groups

    const f32x4* __restrict__ px = (const f32x4*)x;
    const f32x4* __restrict__ py = (const f32x4*)y;
    const f32x4* __restrict__ pv = (const f32x4*)vals;

    f32x4 x0, y0, v0, x1, y1, v1, x2, y2, v2, x3, y3, v3, x4, y4, v4;

#define LOADS(S, idx) do { int _i = (idx); \
        x##S = __builtin_nontemporal_load(&px[_i]); \
        y##S = __builtin_nontemporal_load(&py[_i]); \
        v##S = __builtin_nontemporal_load(&pv[_i]); } while (0)
#define PROC(S) do { \
        process(x##S.x, y##S.x, v##S.x); \
        process(x##S.y, y##S.y, v##S.y); \
        process(x##S.z, y##S.z, v##S.z); \
        process(x##S.w, y##S.w, v##S.w); } while (0)
#define BODY(S) \
        if (i >= n4) break; \
        PROC(S); \
        { int pf = i + 5 * stride; if (pf < n4) LOADS(S, pf); } \
        i += stride;

    // prologue: fill all 5 slots (predicated)
    if (tid + 0 * stride < n4) LOADS(0, tid + 0 * stride);
    if (tid + 1 * stride < n4) LOADS(1, tid + 1 * stride);
    if (tid + 2 * stride < n4) LOADS(2, tid + 2 * stride);
    if (tid + 3 * stride < n4) LOADS(3, tid + 3 * stride);
    if (tid + 4 * stride < n4) LOADS(4, tid + 4 * stride);

    int i = tid;
    for (;;) {
        BODY(0)
        BODY(1)
        BODY(2)
        BODY(3)
        BODY(4)
    }
#undef BODY
#undef PROC
#undef LOADS

    // tail (N % 4 != 0)
    for (int t2 = (n4 << 2) + tid; t2 < n_photons; t2 += stride) {
        process(x[t2], y[t2], vals[t2]);
    }

    __syncthreads();
    float* dst = use_partials
        ? flush_dst + (size_t)(blockIdx.x & (FLUSH_P - 1)) * n_pixels
        : flush_dst;
    for (int k = threadIdx.x; k < n_pixels; k += blockDim.x) {
        float h = hist[k];
        if (h != 0.0f) atomicAdd(&dst[k], h);
    }
}

extern "C" void kernel_launch(void* const* d_in, const int* in_sizes, int n_in,
                              void* d_out, int out_size, void* d_ws, size_t ws_size,
                              hipStream_t stream) {
    const float* x      = (const float*)d_in[0];
    const float* y      = (const float*)d_in[1];
    const float* vals   = (const float*)d_in[2];
    const float* hexs   = (const float*)d_in[4];
    const float* qoff   = (const float*)d_in[5];
    const float* roff   = (const float*)d_in[6];
    const int*   qmin   = (const int*)d_in[7];
    const int*   rmin   = (const int*)d_in[8];

    const int n_photons = in_sizes[0];
    const int lut_elems = in_sizes[3];
    const int Q  = (int)(0.5 + sqrt((double)lut_elems));  // 49
    const int Rh = (Q - 1) / 2;                           // 24
    const int n_pixels = out_size;

    float* out = (float*)d_out;
    float* partials = (float*)d_ws;

    const size_t partial_elems = (size_t)FLUSH_P * (size_t)n_pixels;
    const int use_partials = (ws_size >= partial_elems * sizeof(float)) ? 1 : 0;

    const int threads = 256;
    const int blocks  = 2048;
    const size_t lds_bytes = (size_t)n_pixels * sizeof(float);

    if (use_partials) {
        int zn = (int)partial_elems;
        hex_zero_kernel<<<(zn + 255) / 256, 256, 0, stream>>>(partials, zn);
        hex_bin_kernel<<<blocks, threads, lds_bytes, stream>>>(
            x, y, vals, hexs, qoff, roff, qmin, rmin,
            Rh, n_pixels, n_photons, partials, 1);
        hex_reduce_kernel<<<(n_pixels + 255) / 256, 256, 0, stream>>>(
            partials, out, n_pixels);
    } else {
        hex_zero_kernel<<<(n_pixels + 255) / 256, 256, 0, stream>>>(out, n_pixels);
        hex_bin_kernel<<<blocks, threads, lds_bytes, stream>>>(
            x, y, vals, hexs, qoff, roff, qmin, rmin,
            Rh, n_pixels, n_photons, out, 0);
    }
}